// Round 13
// baseline (700.530 us; speedup 1.0000x reference)
//
#include <hip/hip_runtime.h>
#include <stdint.h>

#define B_ 16
#define C_ 512
#define T_ 4096
#define H_ 8
#define D_ 64
#define SCALE_ 0.125f
#define EPS_ 1e-5f

using ushortT = unsigned short;
using ushort8 = __attribute__((ext_vector_type(8))) unsigned short;
using short8  = __attribute__((ext_vector_type(8))) short;
using floatx4 = __attribute__((ext_vector_type(4))) float;

__device__ __forceinline__ float bf2f(ushortT u) {
  union { unsigned int i; float f; } x; x.i = ((unsigned int)u) << 16; return x.f;
}
__device__ __forceinline__ ushortT f2bf(float f) {
  union { float f; unsigned int i; } x; x.f = f;
  unsigned int r = x.i + 0x7fffu + ((x.i >> 16) & 1u);
  return (ushortT)(r >> 16);
}

// async 16B global->LDS (direct DMA). LDS dest is wave-uniform base + lane*16.
#define GLD16(gp, lp)                                                          \
  __builtin_amdgcn_global_load_lds(                                            \
      (const __attribute__((address_space(1))) unsigned int*)(gp),             \
      (__attribute__((address_space(3))) unsigned int*)(lp), 16, 0, 0)

// ---------------- fp32 -> bf16 convert (weights) ----------------
__global__ __launch_bounds__(256) void cvt_f32_bf16(const float* __restrict__ src,
                                                    ushortT* __restrict__ dst, int n4) {
  int i = blockIdx.x * 256 + threadIdx.x;
  if (i >= n4) return;
  floatx4 v = *(const floatx4*)(src + (size_t)i * 4);
  unsigned int p0 = (unsigned int)f2bf(v[0]) | ((unsigned int)f2bf(v[1]) << 16);
  unsigned int p1 = (unsigned int)f2bf(v[2]) | ((unsigned int)f2bf(v[3]) << 16);
  *(unsigned long long*)(dst + (size_t)i * 4) =
      (unsigned long long)p0 | ((unsigned long long)p1 << 32);
}

// ---------------- zero init ----------------
__global__ void zero_f32(float* p, int n4) {
  int i = blockIdx.x * 256 + threadIdx.x;
  if (i < n4) ((floatx4*)p)[i] = (floatx4){0.f, 0.f, 0.f, 0.f};
}

// ---------------- transpose x[b][c][t] (fp32) -> xT[b][t][c] (bf16) ----------------
__global__ __launch_bounds__(256) void transpose_x(const float* __restrict__ x,
                                                   ushortT* __restrict__ xT) {
  __shared__ ushortT tile[64][65];
  int b = blockIdx.z;
  int t0 = blockIdx.x * 64, c0 = blockIdx.y * 64;
  const float* xb = x + (size_t)b * C_ * T_;
  ushortT* xTb = xT + (size_t)b * T_ * C_;
  for (int i = threadIdx.x; i < 4096; i += 256) {
    int cc = i >> 6, tt = i & 63;
    tile[cc][tt] = f2bf(xb[(size_t)(c0 + cc) * T_ + t0 + tt]);
  }
  __syncthreads();
  for (int i = threadIdx.x; i < 4096; i += 256) {
    int tt = i >> 6, cc = i & 63;
    xTb[(size_t)(t0 + tt) * C_ + c0 + cc] = tile[cc][tt];
  }
}

// ---------------- bf16 GEMM: C[m][n] = sum_k A[m][k]*Bt[n][k] ----------------
// grid: (N/128, M/128, batch), block 256. 128x128 tile, BK=64, 16x16x32 MFMA.
// ASYMMETRIC-OPERAND PIPELINE (r12 post-mortem): every GEMM here has one tiny
// L2-resident operand (W_qkv 1MB / W2 0.5MB / W_q 0.5MB). Only the STREAMED
// operand is LDS-staged (dbuf 2x16KB, GLD16 + counted vmcnt(4), r12-verified
// sync skeleton); the weight operand is read per-fragment straight from
// global (16B loads, L2-hot, compiler-scheduled waits). Halves GLD16s and
// barrier-locked LDS reads; 32KB LDS restores ~5 blocks/CU occupancy.
// STAGE_A=1: stage A (streamed), B direct.  STAGE_A=0: stage B, A direct.
// Staged-operand LDS XOR swizzle (r11-verified: SQ_LDS_BANK_CONFLICT == 0):
// LDS chunk (row,c) holds global chunk (row, c^(row&7)); read chunk
// (kk*4+quad)^(ln&7).  XCD-aware bijective swizzle (nwg%8==0 all launches).
// MODE 2: bf16 out, fused softmax over each 64-col head block * SCALE_ (qT GEMM).
// MODE 3: fp32 out + bias + fused GroupNorm stats (atomicAdd per block).
// MODE 4: bf16 out; k-row blocks (m0<512) get expf applied (defer-max).
template <int MODE, int STAGE_A>
__global__ __launch_bounds__(256) void gemm_bt(
    const ushortT* __restrict__ A, const ushortT* __restrict__ Bt,
    void* __restrict__ Cc, const float* __restrict__ bias,
    float* __restrict__ stats,
    int K, int lda, int ldb, int ldc,
    unsigned long long bsA, unsigned long long bsB, unsigned long long bsC) {
  __shared__ ushortT Ss[2][128 * 64];
  // ---- XCD swizzle: hw linear id -> chunked work id ----
  unsigned int gx = gridDim.x, gy = gridDim.y;
  unsigned int nwg = gx * gy * gridDim.z;
  unsigned int lin = blockIdx.x + gx * (blockIdx.y + gy * blockIdx.z);
  unsigned int cpx = nwg >> 3;
  unsigned int wid = (lin & 7u) * cpx + (lin >> 3);
  unsigned int bx = wid % gx;
  unsigned int tmp = wid / gx;
  unsigned int by = tmp % gy;
  unsigned int bz = tmp / gy;

  const int b = bz;
  A += (size_t)b * bsA; Bt += (size_t)b * bsB;
  const int m0 = by * 128, n0 = bx * 128;
  const int tid = threadIdx.x;
  const int w = tid >> 6, l = tid & 63;
  const int wm = (w >> 1) * 64, wn = (w & 1) * 64;
  const int quad = l >> 4, ln = l & 15;

  // staged operand S (streamed), direct operand D (L2-resident weights)
  const ushortT* Sp = STAGE_A ? A : Bt;
  const ushortT* Dp = STAGE_A ? Bt : A;
  const int ldS = STAGE_A ? lda : ldb;
  const int ldD = STAGE_A ? ldb : lda;
  const int s0  = STAGE_A ? m0 : n0;
  const int d0  = STAGE_A ? n0 : m0;
  const int wS  = STAGE_A ? wm : wn;
  const int wD  = STAGE_A ? wn : wm;

  floatx4 acc[4][4];
#pragma unroll
  for (int i = 0; i < 4; i++)
#pragma unroll
    for (int j = 0; j < 4; j++) acc[i][j] = (floatx4){0.f, 0.f, 0.f, 0.f};

#define STAGE_S(KB, BUF)                                                       \
  {                                                                            \
    _Pragma("unroll")                                                          \
    for (int i_ = 0; i_ < 4; ++i_) {                                           \
      int wci_ = i_ * 256 + (tid & 192);                                       \
      int ci_  = wci_ + (tid & 63);                                            \
      int row_ = ci_ >> 3;                                                     \
      int scol_ = ((ci_ & 7) ^ (row_ & 7)) << 3;                               \
      GLD16(&Sp[(size_t)(s0 + row_) * ldS + (KB) + scol_], &Ss[BUF][wci_ * 8]);\
    }                                                                          \
  }

  STAGE_S(0, 0);
  const int nt = K >> 6;
  for (int t = 0; t < nt; ++t) {
    const int cur = t & 1;
    const int kb = t << 6;
    if (t + 1 < nt) {
      STAGE_S((t + 1) << 6, cur ^ 1);
      asm volatile("s_waitcnt vmcnt(4)" ::: "memory");
    } else {
      asm volatile("s_waitcnt vmcnt(0)" ::: "memory");
    }
    __builtin_amdgcn_s_barrier();
    asm volatile("" ::: "memory");
#pragma unroll
    for (int kk = 0; kk < 2; ++kk) {
      short8 sf[4], df[4];
#pragma unroll
      for (int i = 0; i < 4; i++)
        sf[i] = *(const short8*)(
            &Ss[cur][(wS + i * 16 + ln) * 64 + (((kk * 4 + quad) ^ (ln & 7)) << 3)]);
#pragma unroll
      for (int j = 0; j < 4; j++)
        df[j] = *(const short8*)(
            &Dp[(size_t)(d0 + wD + j * 16 + ln) * ldD + kb + kk * 32 + quad * 8]);
#pragma unroll
      for (int i = 0; i < 4; i++)
#pragma unroll
        for (int j = 0; j < 4; j++)
          acc[i][j] = __builtin_amdgcn_mfma_f32_16x16x32_bf16(
              STAGE_A ? sf[i] : df[i], STAGE_A ? df[j] : sf[j], acc[i][j], 0, 0, 0);
    }
    asm volatile("s_waitcnt lgkmcnt(0)" ::: "memory");
    __builtin_amdgcn_s_barrier();
    asm volatile("" ::: "memory");
  }
#undef STAGE_S

  if constexpr (MODE == 4) {
    const bool isk = (m0 < 512);   // block-uniform
    ushortT* Co = (ushortT*)Cc + (size_t)b * bsC;
#pragma unroll
    for (int i = 0; i < 4; i++)
#pragma unroll
      for (int r = 0; r < 4; r++) {
        int row = m0 + wm + i * 16 + quad * 4 + r;
#pragma unroll
        for (int j = 0; j < 4; j++) {
          int col = n0 + wn + j * 16 + ln;
          float v = acc[i][j][r];
          if (isk) v = expf(v);
          Co[(size_t)row * ldc + col] = f2bf(v);
        }
      }
  } else if constexpr (MODE == 2) {
    // fused softmax over the wave's 64-col head block, then * SCALE_
    ushortT* Co = (ushortT*)Cc + (size_t)b * bsC;
#pragma unroll
    for (int i = 0; i < 4; i++)
#pragma unroll
      for (int r = 0; r < 4; r++) {
        float v0 = acc[i][0][r], v1 = acc[i][1][r], v2 = acc[i][2][r], v3 = acc[i][3][r];
        float mx = fmaxf(fmaxf(v0, v1), fmaxf(v2, v3));
#pragma unroll
        for (int off = 1; off < 16; off <<= 1) mx = fmaxf(mx, __shfl_xor(mx, off));
        float e0 = expf(v0 - mx), e1 = expf(v1 - mx);
        float e2 = expf(v2 - mx), e3 = expf(v3 - mx);
        float s = (e0 + e1) + (e2 + e3);
#pragma unroll
        for (int off = 1; off < 16; off <<= 1) s += __shfl_xor(s, off);
        float inv = SCALE_ / s;
        int row = m0 + wm + i * 16 + quad * 4 + r;
        size_t base = (size_t)row * ldc + n0 + wn + ln;
        Co[base +  0] = f2bf(e0 * inv);
        Co[base + 16] = f2bf(e1 * inv);
        Co[base + 32] = f2bf(e2 * inv);
        Co[base + 48] = f2bf(e3 * inv);
      }
  } else {  // MODE == 3: fp32 + bias + GN stats
    float* Co = (float*)Cc + (size_t)b * bsC;
    float s = 0.f, ss = 0.f;
#pragma unroll
    for (int i = 0; i < 4; i++)
#pragma unroll
      for (int r = 0; r < 4; r++) {
        int row = m0 + wm + i * 16 + quad * 4 + r;
        float bv = bias ? bias[row] : 0.f;
#pragma unroll
        for (int j = 0; j < 4; j++) {
          int col = n0 + wn + j * 16 + ln;
          float v = acc[i][j][r] + bv;
          Co[(size_t)row * ldc + col] = v;
          s += v; ss += v * v;
        }
      }
#pragma unroll
    for (int off = 1; off < 64; off <<= 1) {
      s += __shfl_xor(s, off);
      ss += __shfl_xor(ss, off);
    }
    __shared__ float rs[4], rss[4];
    if (l == 0) { rs[w] = s; rss[w] = ss; }
    __syncthreads();
    if (tid == 0) {
      atomicAdd(&stats[b * 2],     rs[0] + rs[1] + rs[2] + rs[3]);
      atomicAdd(&stats[b * 2 + 1], rss[0] + rss[1] + rss[2] + rss[3]);
    }
  }
}

// ---------------- context: ctRAW[b][h][e][d] += sum_t v[e][t]*ek[d][t] ----------------
// grid (16 slices, 8 h, 16 b), block 64 (one wave). K pre-exp'd by the kv GEMM ->
// pure dual-DMA + MFMA loop. ksum[b][h*64+d] = sum_t ek recovered from the
// B-fragments (each (row,col) covered exactly once per wave per tile).
__global__ __launch_bounds__(64) void context_kv(const ushortT* __restrict__ kv,
                                                 float* __restrict__ ksum,
                                                 float* __restrict__ ct) {
  __shared__ ushortT Vs[64 * 32];
  __shared__ ushortT Ks[64 * 32];
  const int slice = blockIdx.x, h = blockIdx.y, b = blockIdx.z;
  const int t0 = slice * 256;
  const ushortT* vrow = kv + ((size_t)b * 1024 + 512 + h * 64) * T_;
  const ushortT* krow = kv + ((size_t)b * 1024 + h * 64) * T_;
  const int tid = threadIdx.x, quad = tid >> 4, ln = tid & 15;
  float rsum[4] = {0.f, 0.f, 0.f, 0.f};
  floatx4 acc[4][4];
#pragma unroll
  for (int i = 0; i < 4; i++)
#pragma unroll
    for (int j = 0; j < 4; j++) acc[i][j] = (floatx4){0.f, 0.f, 0.f, 0.f};
  for (int kb = 0; kb < 256; kb += 32) {
#pragma unroll
    for (int i = 0; i < 4; ++i) {
      int ci = i * 64 + tid;
      int row = ci >> 2, col = (ci & 3) << 3;
      GLD16(&vrow[(size_t)row * T_ + t0 + kb + col], &Vs[i * 512]);
      GLD16(&krow[(size_t)row * T_ + t0 + kb + col], &Ks[i * 512]);
    }
    __syncthreads();
    short8 af[4], bfv[4];
#pragma unroll
    for (int i = 0; i < 4; i++) af[i] = *(const short8*)(&Vs[(i * 16 + ln) * 32 + quad * 8]);
#pragma unroll
    for (int j = 0; j < 4; j++) {
      bfv[j] = *(const short8*)(&Ks[(j * 16 + ln) * 32 + quad * 8]);
#pragma unroll
      for (int e = 0; e < 8; e++) rsum[j] += bf2f((ushortT)bfv[j][e]);
    }
#pragma unroll
    for (int i = 0; i < 4; i++)
#pragma unroll
      for (int j = 0; j < 4; j++)
        acc[i][j] = __builtin_amdgcn_mfma_f32_16x16x32_bf16(af[i], bfv[j], acc[i][j], 0, 0, 0);
    __syncthreads();
  }
  // ksum: rsum[j] is row (j*16+ln), cols quad*8..+7 of each tile -> reduce quads
  float* ks = ksum + (size_t)b * 512 + h * 64;
#pragma unroll
  for (int j = 0; j < 4; ++j) {
    float s = rsum[j];
    s += __shfl_xor(s, 16);
    s += __shfl_xor(s, 32);
    if (quad == 0) atomicAdd(&ks[j * 16 + ln], s);
  }
  float* ctbh = ct + (size_t)(b * 8 + h) * 4096;
#pragma unroll
  for (int i = 0; i < 4; i++)
#pragma unroll
    for (int r = 0; r < 4; r++) {
      int e = i * 16 + quad * 4 + r;
#pragma unroll
      for (int j = 0; j < 4; j++) {
        int d = j * 16 + ln;
        atomicAdd(&ctbh[e * 64 + d], acc[i][j][r]);
      }
    }
}

// ---------------- W2[b][c][h*64+d] = sum_e Wout[c][h*64+e] * ctRAW[b][h][e][d]/ksum[d] ----------------
// Reassociated attention tail: out = (Wout . ct) . q_sm (attn_out eliminated).
__global__ __launch_bounds__(64) void ct_combine(const ushortT* __restrict__ Wobf,
                                                 const float* __restrict__ ct,
                                                 const float* __restrict__ ksum,
                                                 ushortT* __restrict__ W2) {
  __shared__ ushortT As[64 * 64];   // Wout tile [c][e]
  __shared__ float Cs[64 * 64];     // ct tile [e][d] fp32
  const int c0 = blockIdx.x * 64, h = blockIdx.y, b = blockIdx.z;
  const int tid = threadIdx.x, quad = tid >> 4, ln = tid & 15;
  const float* ctbh = ct + (size_t)(b * 8 + h) * 4096;
#pragma unroll
  for (int i = 0; i < 8; ++i) {
    int ci = i * 64 + tid;
    int row = ci >> 3, col = (ci & 7) << 3;
    *(uint4*)(&As[row * 64 + col]) = *(const uint4*)(&Wobf[(size_t)(c0 + row) * 512 + h * 64 + col]);
  }
#pragma unroll
  for (int i = 0; i < 16; ++i) {
    int off = (i * 64 + tid) * 4;
    *(floatx4*)(&Cs[off]) = *(const floatx4*)(&ctbh[off]);
  }
  const float* ks = ksum + (size_t)b * 512 + h * 64;
  float invd[4];
#pragma unroll
  for (int j = 0; j < 4; j++) invd[j] = 1.f / ks[j * 16 + ln];
  __syncthreads();
  floatx4 acc[4][4];
#pragma unroll
  for (int i = 0; i < 4; i++)
#pragma unroll
    for (int j = 0; j < 4; j++) acc[i][j] = (floatx4){0.f, 0.f, 0.f, 0.f};
#pragma unroll
  for (int kk = 0; kk < 2; ++kk) {
    short8 af[4], bfv[4];
#pragma unroll
    for (int i = 0; i < 4; i++) af[i] = *(const short8*)(&As[(i * 16 + ln) * 64 + kk * 32 + quad * 8]);
#pragma unroll
    for (int j = 0; j < 4; j++) {
#pragma unroll
      for (int e2 = 0; e2 < 8; ++e2)
        bfv[j][e2] = (short)f2bf(Cs[(kk * 32 + quad * 8 + e2) * 64 + j * 16 + ln] * invd[j]);
    }
#pragma unroll
    for (int i = 0; i < 4; i++)
#pragma unroll
      for (int j = 0; j < 4; j++)
        acc[i][j] = __builtin_amdgcn_mfma_f32_16x16x32_bf16(af[i], bfv[j], acc[i][j], 0, 0, 0);
  }
  ushortT* W2b = W2 + (size_t)b * 512 * 512;
#pragma unroll
  for (int i = 0; i < 4; i++)
#pragma unroll
    for (int r = 0; r < 4; r++) {
      int row = c0 + i * 16 + quad * 4 + r;
#pragma unroll
      for (int j = 0; j < 4; j++) {
        int col = h * 64 + j * 16 + ln;
        W2b[(size_t)row * 512 + col] = f2bf(acc[i][j][r]);
      }
    }
}

// ---------------- GroupNorm apply (in-place on fp32 d_out) ----------------
__global__ __launch_bounds__(256) void gn_apply(float* __restrict__ out,
                                                const float* __restrict__ stats,
                                                const float* __restrict__ gnw,
                                                const float* __restrict__ gnb) {
  int b = blockIdx.y;
  int i = blockIdx.x * 256 + threadIdx.x;
  const float invN = 1.f / (float)(C_ * T_);
  float mean = stats[b * 2] * invN;
  float var = stats[b * 2 + 1] * invN - mean * mean;
  float inv = rsqrtf(var + EPS_);
  int c = i >> 9;
  float wv = gnw[c] * inv, bv = gnb[c];
  float* p = out + (size_t)b * C_ * T_ + (size_t)i * 8;
  floatx4 v0 = *(const floatx4*)p;
  floatx4 v1 = *(const floatx4*)(p + 4);
#pragma unroll
  for (int j = 0; j < 4; j++) v0[j] = (v0[j] - mean) * wv + bv;
#pragma unroll
  for (int j = 0; j < 4; j++) v1[j] = (v1[j] - mean) * wv + bv;
  *(floatx4*)p = v0;
  *(floatx4*)(p + 4) = v1;
}

extern "C" void kernel_launch(void* const* d_in, const int* in_sizes, int n_in,
                              void* d_out, int out_size, void* d_ws, size_t ws_size,
                              hipStream_t stream) {
  (void)in_sizes; (void)n_in; (void)out_size; (void)ws_size;
  const float* x    = (const float*)d_in[0];
  const float* Wqkv = (const float*)d_in[1];
  const float* Wout = (const float*)d_in[2];
  const float* bout = (const float*)d_in[3];
  const float* gnw  = (const float*)d_in[4];
  const float* gnb  = (const float*)d_in[5];
  float* out = (float*)d_out;

  // ws layout (132 MB):
  //   xT    bf16 [b][t][512]      @ 0          (64 MB; dead after the two QKV
  //                                             GEMMs -> first 32 KB = ksum
  //                                             fp32[16][512], @1MB = W2
  //                                             bf16[16][512][512] (8 MB))
  //   qT    bf16 [b][t][512]      @ 64M        (64 MB; read by final GEMM)
  //   Wq_bf bf16 [1536][512]      @ 128M
  //   Wo_bf bf16 [512][512]       @ 129.5M
  //   ct    fp32 [16][8][64][64]  @ 130M
  //   stats fp32 [32]             @ 132M
  // kv bf16 [b][1024][t] (128 MB) lives in d_out, dead after context_kv,
  // before the final out-projection GEMM overwrites d_out.
  char* ws = (char*)d_ws;
  ushortT* xT   = (ushortT*)(ws);
  ushortT* qT   = (ushortT*)(ws + 67108864);
  ushortT* Wqbf = (ushortT*)(ws + 134217728);
  ushortT* Wobf = (ushortT*)(ws + 135790592);
  float*   ct   = (float*)(ws + 136314880);
  float* stats  = (float*)(ws + 138412032);
  float* ksum   = (float*)(ws);                 // aliases xT; written after xT dead
  ushortT* W2   = (ushortT*)(ws + 1048576);     // aliases xT+1MB; written after xT dead
  ushortT* kv   = (ushortT*)d_out;

  cvt_f32_bf16<<<768, 256, 0, stream>>>(Wqkv, Wqbf, 196608);
  cvt_f32_bf16<<<256, 256, 0, stream>>>(Wout, Wobf, 65536);
  zero_f32<<<513, 256, 0, stream>>>(ct, 131080);   // ct + stats

  transpose_x<<<dim3(64, 8, 16), 256, 0, stream>>>(x, xT);

  // kv[b][o'][t] = W_qkv[512+o'][:] . xT[b][t][:]; k-rows (o'<512) exp'd
  // A = weights (L2-hot, direct); B = xT (streamed, staged)
  gemm_bt<4, 0><<<dim3(32, 8, 16), 256, 0, stream>>>(
      Wqbf + 512 * 512, xT, kv, nullptr, nullptr, 512, 512, 512, 4096,
      0ULL, (unsigned long long)(T_ * 512), (unsigned long long)(1024 * T_));

  // qT[b][t][o] = xT[b][t][:] . W_qkv[o][:]  + fused softmax over d (*SCALE)
  // A = xT (streamed, staged); B = weights (L2-hot, direct)
  gemm_bt<2, 1><<<dim3(4, 32, 16), 256, 0, stream>>>(
      xT, Wqbf, qT, nullptr, nullptr, 512, 512, 512, 512,
      (unsigned long long)(T_ * 512), 0ULL, (unsigned long long)(T_ * 512));

  // xT dead -> zero ksum (32 KB at ws[0:32K])
  zero_f32<<<8, 256, 0, stream>>>(ksum, 2048);

  context_kv<<<dim3(16, 8, 16), 64, 0, stream>>>(kv, ksum, ct);

  // W2[b] = Wout . (ct[b] * diag(1/ksum))
  ct_combine<<<dim3(8, 8, 16), 64, 0, stream>>>(Wobf, ct, ksum, W2);

  // out[b][c][t] = W2[b][c][:] . qT[b][t][:] + b_out[c], fused GN stats
  // A = W2 (L2-hot, direct); B = qT (streamed, staged)
  gemm_bt<3, 0><<<dim3(32, 4, 16), 256, 0, stream>>>(
      W2, qT, out, bout, stats, 512, 512, 512, 4096,
      (unsigned long long)(512 * 512), (unsigned long long)(T_ * 512),
      (unsigned long long)(512 * T_));

  gn_apply<<<dim3(1024, 16), 256, 0, stream>>>(out, stats, gnw, gnb);
}

// Round 14
// 580.229 us; speedup vs baseline: 1.2073x; 1.2073x over previous
//
#include <hip/hip_runtime.h>
#include <stdint.h>

#define B_ 16
#define C_ 512
#define T_ 4096
#define H_ 8
#define D_ 64
#define SCALE_ 0.125f
#define EPS_ 1e-5f

using ushortT = unsigned short;
using ushort8 = __attribute__((ext_vector_type(8))) unsigned short;
using short8  = __attribute__((ext_vector_type(8))) short;
using floatx4 = __attribute__((ext_vector_type(4))) float;

__device__ __forceinline__ float bf2f(ushortT u) {
  union { unsigned int i; float f; } x; x.i = ((unsigned int)u) << 16; return x.f;
}
__device__ __forceinline__ ushortT f2bf(float f) {
  union { float f; unsigned int i; } x; x.f = f;
  unsigned int r = x.i + 0x7fffu + ((x.i >> 16) & 1u);
  return (ushortT)(r >> 16);
}

// async 16B global->LDS (direct DMA). LDS dest is wave-uniform base + lane*16.
#define GLD16(gp, lp)                                                          \
  __builtin_amdgcn_global_load_lds(                                            \
      (const __attribute__((address_space(1))) unsigned int*)(gp),             \
      (__attribute__((address_space(3))) unsigned int*)(lp), 16, 0, 0)

// ---------------- fp32 -> bf16 convert (weights) ----------------
__global__ __launch_bounds__(256) void cvt_f32_bf16(const float* __restrict__ src,
                                                    ushortT* __restrict__ dst, int n4) {
  int i = blockIdx.x * 256 + threadIdx.x;
  if (i >= n4) return;
  floatx4 v = *(const floatx4*)(src + (size_t)i * 4);
  unsigned int p0 = (unsigned int)f2bf(v[0]) | ((unsigned int)f2bf(v[1]) << 16);
  unsigned int p1 = (unsigned int)f2bf(v[2]) | ((unsigned int)f2bf(v[3]) << 16);
  *(unsigned long long*)(dst + (size_t)i * 4) =
      (unsigned long long)p0 | ((unsigned long long)p1 << 32);
}

// ---------------- zero init ----------------
__global__ void zero_f32(float* p, int n4) {
  int i = blockIdx.x * 256 + threadIdx.x;
  if (i < n4) ((floatx4*)p)[i] = (floatx4){0.f, 0.f, 0.f, 0.f};
}

// ---------------- transpose x[b][c][t] (fp32) -> xT[b][t][c] (bf16) ----------------
__global__ __launch_bounds__(256) void transpose_x(const float* __restrict__ x,
                                                   ushortT* __restrict__ xT) {
  __shared__ ushortT tile[64][65];
  int b = blockIdx.z;
  int t0 = blockIdx.x * 64, c0 = blockIdx.y * 64;
  const float* xb = x + (size_t)b * C_ * T_;
  ushortT* xTb = xT + (size_t)b * T_ * C_;
  for (int i = threadIdx.x; i < 4096; i += 256) {
    int cc = i >> 6, tt = i & 63;
    tile[cc][tt] = f2bf(xb[(size_t)(c0 + cc) * T_ + t0 + tt]);
  }
  __syncthreads();
  for (int i = threadIdx.x; i < 4096; i += 256) {
    int tt = i >> 6, cc = i & 63;
    xTb[(size_t)(t0 + tt) * C_ + c0 + cc] = tile[cc][tt];
  }
}

// ================= GEMM common notes =================
// C[m][n] = sum_k A[m][k]*Bt[n][k]. grid (N/128, M/128, batch), block 256.
// 128x128 tile, BK=64, 16x16x32 MFMA. LDS XOR swizzle (r11-verified,
// SQ_LDS_BANK_CONFLICT==0): LDS chunk (row,c) holds global chunk
// (row, c^(row&7)); frag read uses chunk (kk*4+quad)^(ln&7).
// XCD-aware bijective swizzle (nwg%8==0 for all launches).
// MODE 2: bf16 out + fused softmax per 64-col head block * SCALE_ (qT GEMM).
// MODE 3: fp32 out + bias + fused GroupNorm stats.
// MODE 4: bf16 out; k-row blocks (m0<512) exp'd (defer-max).
// Two variants, both harness-verified:
//   gemm_sb (r11, 32KB LDS single-buffer)  -> qT GEMM (occupancy-sensitive)
//   gemm_db (r12, 64KB LDS dbuf + counted vmcnt(8)) -> the two 128MB GEMMs
//     (r12 measured: 122 us vs sb's 126 us on those dispatches)

#define XCD_SWIZZLE()                                                          \
  unsigned int gx = gridDim.x, gy = gridDim.y;                                 \
  unsigned int nwg = gx * gy * gridDim.z;                                      \
  unsigned int lin = blockIdx.x + gx * (blockIdx.y + gy * blockIdx.z);         \
  unsigned int cpx = nwg >> 3;                                                 \
  unsigned int wid = (lin & 7u) * cpx + (lin >> 3);                            \
  unsigned int bx = wid % gx;                                                  \
  unsigned int tmp = wid / gx;                                                 \
  unsigned int by = tmp % gy;                                                  \
  unsigned int bz = tmp / gy;

#define GEMM_EPILOGUE()                                                        \
  if constexpr (MODE == 4) {                                                   \
    const bool isk = (m0 < 512);                                               \
    ushortT* Co = (ushortT*)Cc + (size_t)b * bsC;                              \
    _Pragma("unroll")                                                          \
    for (int i = 0; i < 4; i++)                                                \
      _Pragma("unroll")                                                        \
      for (int r = 0; r < 4; r++) {                                            \
        int row = m0 + wm + i * 16 + quad * 4 + r;                             \
        _Pragma("unroll")                                                      \
        for (int j = 0; j < 4; j++) {                                          \
          int col = n0 + wn + j * 16 + ln;                                     \
          float v = acc[i][j][r];                                              \
          if (isk) v = expf(v);                                                \
          Co[(size_t)row * ldc + col] = f2bf(v);                               \
        }                                                                      \
      }                                                                        \
  } else if constexpr (MODE == 2) {                                            \
    ushortT* Co = (ushortT*)Cc + (size_t)b * bsC;                              \
    _Pragma("unroll")                                                          \
    for (int i = 0; i < 4; i++)                                                \
      _Pragma("unroll")                                                        \
      for (int r = 0; r < 4; r++) {                                            \
        float v0 = acc[i][0][r], v1 = acc[i][1][r];                            \
        float v2 = acc[i][2][r], v3 = acc[i][3][r];                            \
        float mx = fmaxf(fmaxf(v0, v1), fmaxf(v2, v3));                        \
        _Pragma("unroll")                                                      \
        for (int off = 1; off < 16; off <<= 1) mx = fmaxf(mx, __shfl_xor(mx, off)); \
        float e0 = expf(v0 - mx), e1 = expf(v1 - mx);                          \
        float e2 = expf(v2 - mx), e3 = expf(v3 - mx);                          \
        float s = (e0 + e1) + (e2 + e3);                                       \
        _Pragma("unroll")                                                      \
        for (int off = 1; off < 16; off <<= 1) s += __shfl_xor(s, off);        \
        float inv = SCALE_ / s;                                                \
        int row = m0 + wm + i * 16 + quad * 4 + r;                             \
        size_t base = (size_t)row * ldc + n0 + wn + ln;                        \
        Co[base +  0] = f2bf(e0 * inv);                                        \
        Co[base + 16] = f2bf(e1 * inv);                                        \
        Co[base + 32] = f2bf(e2 * inv);                                        \
        Co[base + 48] = f2bf(e3 * inv);                                        \
      }                                                                        \
  } else {                                                                     \
    float* Co = (float*)Cc + (size_t)b * bsC;                                  \
    float s = 0.f, ss = 0.f;                                                   \
    _Pragma("unroll")                                                          \
    for (int i = 0; i < 4; i++)                                                \
      _Pragma("unroll")                                                        \
      for (int r = 0; r < 4; r++) {                                            \
        int row = m0 + wm + i * 16 + quad * 4 + r;                             \
        float bv = bias ? bias[row] : 0.f;                                     \
        _Pragma("unroll")                                                      \
        for (int j = 0; j < 4; j++) {                                          \
          int col = n0 + wn + j * 16 + ln;                                     \
          float v = acc[i][j][r] + bv;                                         \
          Co[(size_t)row * ldc + col] = v;                                     \
          s += v; ss += v * v;                                                 \
        }                                                                      \
      }                                                                        \
    _Pragma("unroll")                                                          \
    for (int off = 1; off < 64; off <<= 1) {                                   \
      s += __shfl_xor(s, off);                                                 \
      ss += __shfl_xor(ss, off);                                               \
    }                                                                          \
    __shared__ float rs[4], rss[4];                                            \
    if (l == 0) { rs[w] = s; rss[w] = ss; }                                    \
    __syncthreads();                                                           \
    if (tid == 0) {                                                            \
      atomicAdd(&stats[b * 2],     rs[0] + rs[1] + rs[2] + rs[3]);             \
      atomicAdd(&stats[b * 2 + 1], rss[0] + rss[1] + rss[2] + rss[3]);         \
    }                                                                          \
  }

// ---------------- single-buffer variant (r11, 32KB LDS) ----------------
template <int MODE>
__global__ __launch_bounds__(256) void gemm_sb(
    const ushortT* __restrict__ A, const ushortT* __restrict__ Bt,
    void* __restrict__ Cc, const float* __restrict__ bias,
    float* __restrict__ stats,
    int K, int lda, int ldb, int ldc,
    unsigned long long bsA, unsigned long long bsB, unsigned long long bsC) {
  __shared__ ushortT As[128 * 64];
  __shared__ ushortT Bs[128 * 64];
  XCD_SWIZZLE();
  const int b = bz;
  A += (size_t)b * bsA; Bt += (size_t)b * bsB;
  const int m0 = by * 128, n0 = bx * 128;
  const int tid = threadIdx.x;
  const int w = tid >> 6, l = tid & 63;
  const int wm = (w >> 1) * 64, wn = (w & 1) * 64;
  const int quad = l >> 4, ln = l & 15;
  floatx4 acc[4][4];
#pragma unroll
  for (int i = 0; i < 4; i++)
#pragma unroll
    for (int j = 0; j < 4; j++) acc[i][j] = (floatx4){0.f, 0.f, 0.f, 0.f};

  for (int kb = 0; kb < K; kb += 64) {
#pragma unroll
    for (int i = 0; i < 4; ++i) {
      int wci = i * 256 + (tid & 192);
      int ci  = wci + (tid & 63);
      int row = ci >> 3;
      int scol = ((ci & 7) ^ (row & 7)) << 3;
      GLD16(&A[(size_t)(m0 + row) * lda + kb + scol], &As[wci * 8]);
      GLD16(&Bt[(size_t)(n0 + row) * ldb + kb + scol], &Bs[wci * 8]);
    }
    __syncthreads();
#pragma unroll
    for (int kk = 0; kk < 2; ++kk) {
      short8 af[4], bfv[4];
#pragma unroll
      for (int i = 0; i < 4; i++)
        af[i] = *(const short8*)(
            &As[(wm + i * 16 + ln) * 64 + (((kk * 4 + quad) ^ (ln & 7)) << 3)]);
#pragma unroll
      for (int j = 0; j < 4; j++)
        bfv[j] = *(const short8*)(
            &Bs[(wn + j * 16 + ln) * 64 + (((kk * 4 + quad) ^ (ln & 7)) << 3)]);
#pragma unroll
      for (int i = 0; i < 4; i++)
#pragma unroll
        for (int j = 0; j < 4; j++)
          acc[i][j] = __builtin_amdgcn_mfma_f32_16x16x32_bf16(af[i], bfv[j], acc[i][j], 0, 0, 0);
    }
    __syncthreads();
  }
  GEMM_EPILOGUE();
}

// ---------------- double-buffer counted-vmcnt variant (r12, 64KB LDS) ----------------
#define STAGE_TILE(KB, BUF)                                                    \
  {                                                                            \
    _Pragma("unroll")                                                          \
    for (int i_ = 0; i_ < 4; ++i_) {                                           \
      int wci_ = i_ * 256 + (tid & 192);                                       \
      int ci_  = wci_ + (tid & 63);                                            \
      int row_ = ci_ >> 3;                                                     \
      int scol_ = ((ci_ & 7) ^ (row_ & 7)) << 3;                               \
      GLD16(&A[(size_t)(m0 + row_) * lda + (KB) + scol_], &As[BUF][wci_ * 8]); \
      GLD16(&Bt[(size_t)(n0 + row_) * ldb + (KB) + scol_], &Bs[BUF][wci_ * 8]);\
    }                                                                          \
  }

template <int MODE>
__global__ __launch_bounds__(256) void gemm_db(
    const ushortT* __restrict__ A, const ushortT* __restrict__ Bt,
    void* __restrict__ Cc, const float* __restrict__ bias,
    float* __restrict__ stats,
    int K, int lda, int ldb, int ldc,
    unsigned long long bsA, unsigned long long bsB, unsigned long long bsC) {
  __shared__ ushortT As[2][128 * 64];
  __shared__ ushortT Bs[2][128 * 64];
  XCD_SWIZZLE();
  const int b = bz;
  A += (size_t)b * bsA; Bt += (size_t)b * bsB;
  const int m0 = by * 128, n0 = bx * 128;
  const int tid = threadIdx.x;
  const int w = tid >> 6, l = tid & 63;
  const int wm = (w >> 1) * 64, wn = (w & 1) * 64;
  const int quad = l >> 4, ln = l & 15;
  floatx4 acc[4][4];
#pragma unroll
  for (int i = 0; i < 4; i++)
#pragma unroll
    for (int j = 0; j < 4; j++) acc[i][j] = (floatx4){0.f, 0.f, 0.f, 0.f};

  STAGE_TILE(0, 0);
  const int nt = K >> 6;
  for (int t = 0; t < nt; ++t) {
    const int cur = t & 1;
    if (t + 1 < nt) {
      STAGE_TILE((t + 1) << 6, cur ^ 1);
      asm volatile("s_waitcnt vmcnt(8)" ::: "memory");
    } else {
      asm volatile("s_waitcnt vmcnt(0)" ::: "memory");
    }
    __builtin_amdgcn_s_barrier();
    asm volatile("" ::: "memory");
#pragma unroll
    for (int kk = 0; kk < 2; ++kk) {
      short8 af[4], bfv[4];
#pragma unroll
      for (int i = 0; i < 4; i++)
        af[i] = *(const short8*)(
            &As[cur][(wm + i * 16 + ln) * 64 + (((kk * 4 + quad) ^ (ln & 7)) << 3)]);
#pragma unroll
      for (int j = 0; j < 4; j++)
        bfv[j] = *(const short8*)(
            &Bs[cur][(wn + j * 16 + ln) * 64 + (((kk * 4 + quad) ^ (ln & 7)) << 3)]);
#pragma unroll
      for (int i = 0; i < 4; i++)
#pragma unroll
        for (int j = 0; j < 4; j++)
          acc[i][j] = __builtin_amdgcn_mfma_f32_16x16x32_bf16(af[i], bfv[j], acc[i][j], 0, 0, 0);
    }
    asm volatile("s_waitcnt lgkmcnt(0)" ::: "memory");
    __builtin_amdgcn_s_barrier();
    asm volatile("" ::: "memory");
  }
  GEMM_EPILOGUE();
}

// ---------------- context: ctRAW[b][h][e][d] += sum_t v[e][t]*ek[d][t] ----------------
// grid (16 slices, 8 h, 16 b), block 64 (one wave). K pre-exp'd by the kv GEMM ->
// pure dual-DMA + MFMA loop. ksum[b][h*64+d] = sum_t ek recovered from the
// B-fragments (each (row,col) covered exactly once per wave per tile).
__global__ __launch_bounds__(64) void context_kv(const ushortT* __restrict__ kv,
                                                 float* __restrict__ ksum,
                                                 float* __restrict__ ct) {
  __shared__ ushortT Vs[64 * 32];
  __shared__ ushortT Ks[64 * 32];
  const int slice = blockIdx.x, h = blockIdx.y, b = blockIdx.z;
  const int t0 = slice * 256;
  const ushortT* vrow = kv + ((size_t)b * 1024 + 512 + h * 64) * T_;
  const ushortT* krow = kv + ((size_t)b * 1024 + h * 64) * T_;
  const int tid = threadIdx.x, quad = tid >> 4, ln = tid & 15;
  float rsum[4] = {0.f, 0.f, 0.f, 0.f};
  floatx4 acc[4][4];
#pragma unroll
  for (int i = 0; i < 4; i++)
#pragma unroll
    for (int j = 0; j < 4; j++) acc[i][j] = (floatx4){0.f, 0.f, 0.f, 0.f};
  for (int kb = 0; kb < 256; kb += 32) {
#pragma unroll
    for (int i = 0; i < 4; ++i) {
      int ci = i * 64 + tid;
      int row = ci >> 2, col = (ci & 3) << 3;
      GLD16(&vrow[(size_t)row * T_ + t0 + kb + col], &Vs[i * 512]);
      GLD16(&krow[(size_t)row * T_ + t0 + kb + col], &Ks[i * 512]);
    }
    __syncthreads();
    short8 af[4], bfv[4];
#pragma unroll
    for (int i = 0; i < 4; i++) af[i] = *(const short8*)(&Vs[(i * 16 + ln) * 32 + quad * 8]);
#pragma unroll
    for (int j = 0; j < 4; j++) {
      bfv[j] = *(const short8*)(&Ks[(j * 16 + ln) * 32 + quad * 8]);
#pragma unroll
      for (int e = 0; e < 8; e++) rsum[j] += bf2f((ushortT)bfv[j][e]);
    }
#pragma unroll
    for (int i = 0; i < 4; i++)
#pragma unroll
      for (int j = 0; j < 4; j++)
        acc[i][j] = __builtin_amdgcn_mfma_f32_16x16x32_bf16(af[i], bfv[j], acc[i][j], 0, 0, 0);
    __syncthreads();
  }
  // ksum: rsum[j] is row (j*16+ln), cols quad*8..+7 of each tile -> reduce quads
  float* ks = ksum + (size_t)b * 512 + h * 64;
#pragma unroll
  for (int j = 0; j < 4; ++j) {
    float s = rsum[j];
    s += __shfl_xor(s, 16);
    s += __shfl_xor(s, 32);
    if (quad == 0) atomicAdd(&ks[j * 16 + ln], s);
  }
  float* ctbh = ct + (size_t)(b * 8 + h) * 4096;
#pragma unroll
  for (int i = 0; i < 4; i++)
#pragma unroll
    for (int r = 0; r < 4; r++) {
      int e = i * 16 + quad * 4 + r;
#pragma unroll
      for (int j = 0; j < 4; j++) {
        int d = j * 16 + ln;
        atomicAdd(&ctbh[e * 64 + d], acc[i][j][r]);
      }
    }
}

// ---------------- W2[b][c][h*64+d] = sum_e Wout[c][h*64+e] * ctRAW[b][h][e][d]/ksum[d] ----------------
// Reassociated attention tail: out = (Wout . ct) . q_sm (attn_out eliminated).
__global__ __launch_bounds__(64) void ct_combine(const ushortT* __restrict__ Wobf,
                                                 const float* __restrict__ ct,
                                                 const float* __restrict__ ksum,
                                                 ushortT* __restrict__ W2) {
  __shared__ ushortT As[64 * 64];   // Wout tile [c][e]
  __shared__ float Cs[64 * 64];     // ct tile [e][d] fp32
  const int c0 = blockIdx.x * 64, h = blockIdx.y, b = blockIdx.z;
  const int tid = threadIdx.x, quad = tid >> 4, ln = tid & 15;
  const float* ctbh = ct + (size_t)(b * 8 + h) * 4096;
#pragma unroll
  for (int i = 0; i < 8; ++i) {
    int ci = i * 64 + tid;
    int row = ci >> 3, col = (ci & 7) << 3;
    *(uint4*)(&As[row * 64 + col]) = *(const uint4*)(&Wobf[(size_t)(c0 + row) * 512 + h * 64 + col]);
  }
#pragma unroll
  for (int i = 0; i < 16; ++i) {
    int off = (i * 64 + tid) * 4;
    *(floatx4*)(&Cs[off]) = *(const floatx4*)(&ctbh[off]);
  }
  const float* ks = ksum + (size_t)b * 512 + h * 64;
  float invd[4];
#pragma unroll
  for (int j = 0; j < 4; j++) invd[j] = 1.f / ks[j * 16 + ln];
  __syncthreads();
  floatx4 acc[4][4];
#pragma unroll
  for (int i = 0; i < 4; i++)
#pragma unroll
    for (int j = 0; j < 4; j++) acc[i][j] = (floatx4){0.f, 0.f, 0.f, 0.f};
#pragma unroll
  for (int kk = 0; kk < 2; ++kk) {
    short8 af[4], bfv[4];
#pragma unroll
    for (int i = 0; i < 4; i++) af[i] = *(const short8*)(&As[(i * 16 + ln) * 64 + kk * 32 + quad * 8]);
#pragma unroll
    for (int j = 0; j < 4; j++) {
#pragma unroll
      for (int e2 = 0; e2 < 8; ++e2)
        bfv[j][e2] = (short)f2bf(Cs[(kk * 32 + quad * 8 + e2) * 64 + j * 16 + ln] * invd[j]);
    }
#pragma unroll
    for (int i = 0; i < 4; i++)
#pragma unroll
      for (int j = 0; j < 4; j++)
        acc[i][j] = __builtin_amdgcn_mfma_f32_16x16x32_bf16(af[i], bfv[j], acc[i][j], 0, 0, 0);
  }
  ushortT* W2b = W2 + (size_t)b * 512 * 512;
#pragma unroll
  for (int i = 0; i < 4; i++)
#pragma unroll
    for (int r = 0; r < 4; r++) {
      int row = c0 + i * 16 + quad * 4 + r;
#pragma unroll
      for (int j = 0; j < 4; j++) {
        int col = h * 64 + j * 16 + ln;
        W2b[(size_t)row * 512 + col] = f2bf(acc[i][j][r]);
      }
    }
}

// ---------------- GroupNorm apply (in-place on fp32 d_out) ----------------
__global__ __launch_bounds__(256) void gn_apply(float* __restrict__ out,
                                                const float* __restrict__ stats,
                                                const float* __restrict__ gnw,
                                                const float* __restrict__ gnb) {
  int b = blockIdx.y;
  int i = blockIdx.x * 256 + threadIdx.x;
  const float invN = 1.f / (float)(C_ * T_);
  float mean = stats[b * 2] * invN;
  float var = stats[b * 2 + 1] * invN - mean * mean;
  float inv = rsqrtf(var + EPS_);
  int c = i >> 9;
  float wv = gnw[c] * inv, bv = gnb[c];
  float* p = out + (size_t)b * C_ * T_ + (size_t)i * 8;
  floatx4 v0 = *(const floatx4*)p;
  floatx4 v1 = *(const floatx4*)(p + 4);
#pragma unroll
  for (int j = 0; j < 4; j++) v0[j] = (v0[j] - mean) * wv + bv;
#pragma unroll
  for (int j = 0; j < 4; j++) v1[j] = (v1[j] - mean) * wv + bv;
  *(floatx4*)p = v0;
  *(floatx4*)(p + 4) = v1;
}

extern "C" void kernel_launch(void* const* d_in, const int* in_sizes, int n_in,
                              void* d_out, int out_size, void* d_ws, size_t ws_size,
                              hipStream_t stream) {
  (void)in_sizes; (void)n_in; (void)out_size; (void)ws_size;
  const float* x    = (const float*)d_in[0];
  const float* Wqkv = (const float*)d_in[1];
  const float* Wout = (const float*)d_in[2];
  const float* bout = (const float*)d_in[3];
  const float* gnw  = (const float*)d_in[4];
  const float* gnb  = (const float*)d_in[5];
  float* out = (float*)d_out;

  // ws layout (132 MB):
  //   xT    bf16 [b][t][512]      @ 0          (64 MB; dead after the two QKV
  //                                             GEMMs -> first 32 KB = ksum
  //                                             fp32[16][512], @1MB = W2
  //                                             bf16[16][512][512] (8 MB))
  //   qT    bf16 [b][t][512]      @ 64M        (64 MB; read by final GEMM)
  //   Wq_bf bf16 [1536][512]      @ 128M
  //   Wo_bf bf16 [512][512]       @ 129.5M
  //   ct    fp32 [16][8][64][64]  @ 130M
  //   stats fp32 [32]             @ 132M
  // kv bf16 [b][1024][t] (128 MB) lives in d_out, dead after context_kv,
  // before the final out-projection GEMM overwrites d_out.
  char* ws = (char*)d_ws;
  ushortT* xT   = (ushortT*)(ws);
  ushortT* qT   = (ushortT*)(ws + 67108864);
  ushortT* Wqbf = (ushortT*)(ws + 134217728);
  ushortT* Wobf = (ushortT*)(ws + 135790592);
  float*   ct   = (float*)(ws + 136314880);
  float* stats  = (float*)(ws + 138412032);
  float* ksum   = (float*)(ws);                 // aliases xT; written after xT dead
  ushortT* W2   = (ushortT*)(ws + 1048576);     // aliases xT+1MB; written after xT dead
  ushortT* kv   = (ushortT*)d_out;

  cvt_f32_bf16<<<768, 256, 0, stream>>>(Wqkv, Wqbf, 196608);
  cvt_f32_bf16<<<256, 256, 0, stream>>>(Wout, Wobf, 65536);
  zero_f32<<<513, 256, 0, stream>>>(ct, 131080);   // ct + stats

  transpose_x<<<dim3(64, 8, 16), 256, 0, stream>>>(x, xT);

  // kv[b][o'][t] = W_qkv[512+o'][:] . xT[b][t][:]; k-rows (o'<512) exp'd
  gemm_db<4><<<dim3(32, 8, 16), 256, 0, stream>>>(
      Wqbf + 512 * 512, xT, kv, nullptr, nullptr, 512, 512, 512, 4096,
      0ULL, (unsigned long long)(T_ * 512), (unsigned long long)(1024 * T_));

  // qT[b][t][o] = xT[b][t][:] . W_qkv[o][:]  + fused softmax over d (*SCALE)
  gemm_sb<2><<<dim3(4, 32, 16), 256, 0, stream>>>(
      xT, Wqbf, qT, nullptr, nullptr, 512, 512, 512, 512,
      (unsigned long long)(T_ * 512), 0ULL, (unsigned long long)(T_ * 512));

  // xT dead -> zero ksum (32 KB at ws[0:32K])
  zero_f32<<<8, 256, 0, stream>>>(ksum, 2048);

  context_kv<<<dim3(16, 8, 16), 64, 0, stream>>>(kv, ksum, ct);

  // W2[b] = Wout . (ct[b] * diag(1/ksum))
  ct_combine<<<dim3(8, 8, 16), 64, 0, stream>>>(Wobf, ct, ksum, W2);

  // out[b][c][t] = W2[b][c][:] . qT[b][t][:] + b_out[c], fused GN stats
  gemm_db<3><<<dim3(32, 4, 16), 256, 0, stream>>>(
      W2, qT, out, bout, stats, 512, 512, 512, 4096,
      (unsigned long long)(512 * 512), (unsigned long long)(T_ * 512),
      (unsigned long long)(512 * T_));

  gn_apply<<<dim3(1024, 16), 256, 0, stream>>>(out, stats, gnw, gnb);
}